// Round 1
// baseline (102.957 us; speedup 1.0000x reference)
//
#include <hip/hip_runtime.h>
#include <math.h>

#define OUT_H 152
#define OUT_W 272
#define HW 41344
#define NOBJ 64
#define NB 8
#define NID 537
#define EMB 256

// workspace float offsets
#define OF_CTX 0
#define OF_CTY 512
#define OF_RAD 1024
#define OF_INV 1536
#define OF_VM  2048
#define OF_V   2560
#define OF_WH  3072   /* 512*8 = 4096 floats */
#define OF_MSUM 7168
#define OF_POS  7176
#define OF_NEG  7184
#define OF_NP   7192
#define OF_REG  7200
#define OF_VIS  7208
#define OF_ID   7216
#define OF_INT  7424  /* int region: ind[512], ids[512] */
#define WS_FLOATS (7424 + 1024)

__device__ inline float waveRedSum(float v) {
  for (int off = 32; off; off >>= 1) v += __shfl_down(v, off, 64);
  return v;
}
__device__ inline float waveRedMax(float v) {
  for (int off = 32; off; off >>= 1) v = fmaxf(v, __shfl_down(v, off, 64));
  return v;
}

__global__ void prep_kernel(const float* __restrict__ ann1,
                            const float* __restrict__ ann2,
                            float* __restrict__ F) {
  int b = blockIdx.x;
  int i = threadIdx.x; // 0..63
  const float* a1 = ann1 + (b * NOBJ + i) * 8;
  const float* A2 = ann2 + b * NOBJ * 8;

  float cx_raw = a1[0] * (float)OUT_W;
  float cy_raw = a1[1] * (float)OUT_H;
  float w = a1[2] * (float)OUT_W;
  float h = a1[3] * (float)OUT_H;
  float x1 = cx_raw - 0.5f * w, y1 = cy_raw - 0.5f * h;
  float x2 = x1 + w, y2 = y1 + h;
  float cx = fminf(fmaxf(cx_raw, 0.f), (float)(OUT_W - 1));
  float cy = fminf(fmaxf(cy_raw, 0.f), (float)(OUT_H - 1));
  int ctx = (int)cx, cty = (int)cy;

  float hc = ceilf(h), wc = ceilf(w);
  float b1 = hc + wc;
  float c1 = wc * hc * 0.3f / 1.7f;
  float r1 = (b1 + sqrtf(fmaxf(b1 * b1 - 4.f * c1, 0.f))) * 0.5f;
  float b2 = 2.f * (hc + wc);
  float c2 = 0.3f * wc * hc;
  float r2 = (b2 + sqrtf(fmaxf(b2 * b2 - 16.f * c2, 0.f))) * 0.5f;
  float b3 = -1.4f * (hc + wc);
  float c3 = -0.3f * wc * hc;
  float r3 = (b3 + sqrtf(fmaxf(b3 * b3 - 11.2f * c3, 0.f))) * 0.5f;
  float radius = fmaxf(floorf(fminf(fminf(r1, r2), r3)), 0.f);
  float sigma = (2.f * radius + 1.f) / 6.f;
  float inv2s2 = 1.f / (2.f * sigma * sigma);

  // PID matching (first match, like argmax over bool)
  float pid = a1[5];
  int jm = -1;
  for (int j = 0; j < NOBJ; ++j) {
    if (A2[j * 8 + 5] == pid) { jm = j; break; }
  }
  bool has = (jm >= 0);
  const float* t1 = A2 + (has ? jm : 0) * 8;
  float cx2 = t1[0] * (float)OUT_W, cy2 = t1[1] * (float)OUT_H;
  float w2 = t1[2] * (float)OUT_W, h2 = t1[3] * (float)OUT_H;
  float x1t = cx2 - 0.5f * w2, y1t = cy2 - 0.5f * h2;
  float x2t = x1t + w2, y2t = y1t + h2;

  bool valid = has && (h > 0.f) && (w > 0.f) && (h2 > 0.f) && (w2 > 0.f);
  float vm = valid ? 1.f : 0.f;
  float cxf = (float)ctx, cyf = (float)cty;

  int gi = b * NOBJ + i;
  F[OF_CTX + gi] = cxf;
  F[OF_CTY + gi] = cyf;
  F[OF_RAD + gi] = radius;
  F[OF_INV + gi] = inv2s2;
  F[OF_VM + gi] = vm;
  F[OF_V + gi] = a1[6] * vm;
  float* wh = F + OF_WH + gi * 8;
  wh[0] = (cxf - x1) * vm;  wh[1] = (x2 - cxf) * vm;
  wh[2] = (cyf - y1) * vm;  wh[3] = (y2 - cyf) * vm;
  wh[4] = (cxf - x1t) * vm; wh[5] = (x2t - cxf) * vm;
  wh[6] = (cyf - y1t) * vm; wh[7] = (y2t - cyf) * vm;
  int* I = (int*)(F + OF_INT);
  I[gi] = valid ? (cty * OUT_W + ctx) : 0;
  I[512 + gi] = valid ? (int)pid : 0;

  float s = waveRedSum(vm);
  if (i == 0) F[OF_MSUM + b] = s;
}

__global__ void focal_kernel(const float* __restrict__ cls,
                             float* __restrict__ F) {
  int b = blockIdx.y;
  int p = blockIdx.x * blockDim.x + threadIdx.x;
  __shared__ float s_ctx[64], s_cty[64], s_rad[64], s_inv[64];
  if (threadIdx.x < 64) {
    int gi = b * NOBJ + threadIdx.x;
    s_ctx[threadIdx.x] = F[OF_CTX + gi];
    s_cty[threadIdx.x] = F[OF_CTY + gi];
    s_rad[threadIdx.x] = F[OF_RAD + gi];
    s_inv[threadIdx.x] = F[OF_INV + gi];
  }
  __syncthreads();

  float pos_l = 0.f, neg_l = 0.f, npos = 0.f;
  if (p < HW) {
    float xf = (float)(p % OUT_W);
    float yf = (float)(p / OUT_W);
    float gt = 0.f;
    #pragma unroll 8
    for (int o = 0; o < 64; ++o) {
      float dy = yf - s_cty[o];
      float dx = xf - s_ctx[o];
      float r = s_rad[o];
      if (fabsf(dy) <= r && fabsf(dx) <= r) {
        gt = fmaxf(gt, expf(-(dy * dy + dx * dx) * s_inv[o]));
      }
    }
    float x = cls[b * HW + p];
    float pr = 1.f / (1.f + expf(-x));
    pr = fminf(fmaxf(pr, 1e-4f), 0.9999f);
    if (gt == 1.f) {
      float om = 1.f - pr;
      pos_l = logf(pr) * om * om;
      npos = 1.f;
    } else {
      float omg = 1.f - gt;
      float w4 = omg * omg;
      w4 *= w4;
      neg_l = logf(1.f - pr) * pr * pr * w4;
    }
  }

  __shared__ float red[3][4];
  int wid = threadIdx.x >> 6, lane = threadIdx.x & 63;
  float a = waveRedSum(pos_l);
  float c = waveRedSum(neg_l);
  float n = waveRedSum(npos);
  if (lane == 0) { red[0][wid] = a; red[1][wid] = c; red[2][wid] = n; }
  __syncthreads();
  if (threadIdx.x == 0) {
    float pa = 0.f, pc = 0.f, pn = 0.f;
    for (int k = 0; k < 4; ++k) { pa += red[0][k]; pc += red[1][k]; pn += red[2][k]; }
    atomicAdd(&F[OF_POS + b], pa);
    atomicAdd(&F[OF_NEG + b], pc);
    atomicAdd(&F[OF_NP + b], pn);
  }
}

__global__ void regvis_kernel(const float* __restrict__ reg,
                              const float* __restrict__ viss,
                              float* __restrict__ F) {
  int b = blockIdx.x, i = threadIdx.x, gi = b * 64 + i;
  const int* I = (const int*)(F + OF_INT);
  float vm = F[OF_VM + gi];
  float rsum = 0.f, vsum = 0.f;
  if (vm > 0.f) {
    int ind = I[gi];
    const float* whp = F + OF_WH + gi * 8;
    for (int c = 0; c < 8; ++c) {
      float pred = reg[(b * 8 + c) * HW + ind];
      float d = fabsf(pred - whp[c]);
      rsum += (d < 1.f) ? 0.5f * d * d : d - 0.5f;
    }
    float s = 1.f / (1.f + expf(-viss[b * HW + ind]));
    s = fminf(fmaxf(s, 1e-4f), 0.9999f);
    float d = fabsf(s - F[OF_V + gi]);
    vsum = (d < 1.f) ? 0.5f * d * d : d - 0.5f;
  }
  rsum = waveRedSum(rsum);
  vsum = waveRedSum(vsum);
  if (i == 0) { F[OF_REG + b] = rsum; F[OF_VIS + b] = vsum; }
}

__global__ void id_kernel(const float* __restrict__ identis,
                          const float* __restrict__ W_id,
                          const float* __restrict__ b_id,
                          float* __restrict__ F) {
  int o = blockIdx.x, b = blockIdx.y, gi = b * 64 + o;
  if (F[OF_VM + gi] == 0.f) return;
  const int* I = (const int*)(F + OF_INT);
  int ind = I[gi], id = I[512 + gi];
  int t = threadIdx.x;
  __shared__ float shf[EMB];
  __shared__ float slog[544];
  __shared__ float red4[4];
  int wid = t >> 6, lane = t & 63;

  float f = identis[(size_t)b * EMB * HW + (size_t)t * HW + ind];
  float n2 = waveRedSum(f * f);
  if (lane == 0) red4[wid] = n2;
  __syncthreads();
  float norm2 = red4[0] + red4[1] + red4[2] + red4[3];
  const float EMB_SCALE = 1.41421356237309515f * logf(536.0f);
  float scale = EMB_SCALE / fmaxf(sqrtf(norm2), 1e-12f);
  shf[t] = f * scale;
  __syncthreads();

  for (int c = t; c < NID; c += 256) {
    float acc = b_id[c];
    const float* wr = W_id + (size_t)c * EMB;
    #pragma unroll 4
    for (int k = 0; k < EMB; k += 4) {
      acc += shf[k] * wr[k] + shf[k + 1] * wr[k + 1] +
             shf[k + 2] * wr[k + 2] + shf[k + 3] * wr[k + 3];
    }
    slog[c] = acc;
  }
  __syncthreads();

  float mx = -1e30f;
  for (int c = t; c < NID; c += 256) mx = fmaxf(mx, slog[c]);
  mx = waveRedMax(mx);
  __syncthreads();           // protect red4 reuse
  if (lane == 0) red4[wid] = mx;
  __syncthreads();
  mx = fmaxf(fmaxf(red4[0], red4[1]), fmaxf(red4[2], red4[3]));

  float se = 0.f;
  for (int c = t; c < NID; c += 256) se += expf(slog[c] - mx);
  se = waveRedSum(se);
  __syncthreads();           // protect red4 reuse
  if (lane == 0) red4[wid] = se;
  __syncthreads();

  if (t == 0) {
    float sesum = red4[0] + red4[1] + red4[2] + red4[3];
    float lse = mx + logf(sesum);
    float logp = slog[id] - lse;
    float nll = -F[OF_V + gi] * logp;
    atomicAdd(&F[OF_ID + b], nll);
  }
}

__global__ void final_kernel(const float* __restrict__ F,
                             const float* __restrict__ s_det,
                             const float* __restrict__ s_id,
                             float* __restrict__ out) {
  float cl = 0.f, rl = 0.f, vl = 0.f, il = 0.f;
  for (int b = 0; b < NB; ++b) {
    float np = F[OF_NP + b], pl = F[OF_POS + b], nl = F[OF_NEG + b];
    cl += (np > 0.f) ? (-(pl + nl) / fmaxf(np, 1.f)) : (-nl);
    float ms = F[OF_MSUM + b];
    rl += F[OF_REG + b] / (ms + 0.0001f);
    vl += F[OF_VIS + b] / (ms + 0.0001f);
    il += F[OF_ID + b] / fmaxf(ms, 1.f);
  }
  out[0] = cl / 8.f;
  out[1] = rl / 8.f;
  out[2] = vl / 8.f;
  out[3] = il / 8.f;
  out[4] = s_det[0];
  out[5] = s_id[0];
}

extern "C" void kernel_launch(void* const* d_in, const int* in_sizes, int n_in,
                              void* d_out, int out_size, void* d_ws, size_t ws_size,
                              hipStream_t stream) {
  const float* cls     = (const float*)d_in[0];
  const float* reg     = (const float*)d_in[1];
  const float* viss    = (const float*)d_in[2];
  const float* identis = (const float*)d_in[3];
  const float* ann1    = (const float*)d_in[4];
  const float* ann2    = (const float*)d_in[5];
  const float* W_id    = (const float*)d_in[6];
  const float* b_id    = (const float*)d_in[7];
  const float* s_det   = (const float*)d_in[8];
  const float* s_id    = (const float*)d_in[9];
  float* F = (float*)d_ws;

  hipMemsetAsync(d_ws, 0, WS_FLOATS * sizeof(float), stream);
  prep_kernel<<<NB, 64, 0, stream>>>(ann1, ann2, F);
  dim3 fg((HW + 255) / 256, NB);
  focal_kernel<<<fg, 256, 0, stream>>>(cls, F);
  regvis_kernel<<<NB, 64, 0, stream>>>(reg, viss, F);
  id_kernel<<<dim3(NOBJ, NB), 256, 0, stream>>>(identis, W_id, b_id, F);
  final_kernel<<<1, 1, 0, stream>>>(F, s_det, s_id, (float*)d_out);
}

// Round 2
// 60.583 us; speedup vs baseline: 1.6994x; 1.6994x over previous
//
#include <hip/hip_runtime.h>
#include <math.h>

#define OUT_H 152
#define OUT_W 272
#define HW 41344
#define NOBJ 64
#define NB 8
#define NID 537
#define EMB 256

#define NFBLK 162                 /* focal blocks per batch: ceil(41344/256) */
#define NFOCAL (NFBLK * NB)       /* 1296 */
#define NIDBLK (NB * NOBJ)        /* 512 */

/* workspace float offsets — every slot written by kernel A before B reads */
#define OF_FP    0                /* 1296*3 focal partials (pos,neg,np) */
#define OF_IDNLL (NFOCAL * 3)     /* 512 per-object id NLL */

__device__ inline float waveRedSum(float v) {
  for (int off = 32; off; off >>= 1) v += __shfl_down(v, off, 64);
  return v;
}
__device__ inline float waveRedMax(float v) {
  for (int off = 32; off; off >>= 1) v = fmaxf(v, __shfl_down(v, off, 64));
  return v;
}

struct PrepOut {
  float cxf, cyf, radius, inv2s2, vm, v;
  float wh[8];
  int ind, id;
};

__device__ __forceinline__ PrepOut prep_obj(const float* __restrict__ ann1,
                                            const float* __restrict__ ann2,
                                            int b, int i) {
  const float* a1 = ann1 + (b * NOBJ + i) * 8;
  const float* A2 = ann2 + b * NOBJ * 8;

  float cx_raw = a1[0] * (float)OUT_W;
  float cy_raw = a1[1] * (float)OUT_H;
  float w = a1[2] * (float)OUT_W;
  float h = a1[3] * (float)OUT_H;
  float x1 = cx_raw - 0.5f * w, y1 = cy_raw - 0.5f * h;
  float x2 = x1 + w, y2 = y1 + h;
  float cx = fminf(fmaxf(cx_raw, 0.f), (float)(OUT_W - 1));
  float cy = fminf(fmaxf(cy_raw, 0.f), (float)(OUT_H - 1));
  int ctx = (int)cx, cty = (int)cy;

  float hc = ceilf(h), wc = ceilf(w);
  float b1 = hc + wc;
  float c1 = wc * hc * 0.3f / 1.7f;
  float r1 = (b1 + sqrtf(fmaxf(b1 * b1 - 4.f * c1, 0.f))) * 0.5f;
  float b2 = 2.f * (hc + wc);
  float c2 = 0.3f * wc * hc;
  float r2 = (b2 + sqrtf(fmaxf(b2 * b2 - 16.f * c2, 0.f))) * 0.5f;
  float b3 = -1.4f * (hc + wc);
  float c3 = -0.3f * wc * hc;
  float r3 = (b3 + sqrtf(fmaxf(b3 * b3 - 11.2f * c3, 0.f))) * 0.5f;
  float radius = fmaxf(floorf(fminf(fminf(r1, r2), r3)), 0.f);
  float sigma = (2.f * radius + 1.f) / 6.f;

  PrepOut P;
  P.cxf = (float)ctx;
  P.cyf = (float)cty;
  P.radius = radius;
  P.inv2s2 = 1.f / (2.f * sigma * sigma);

  float pid = a1[5];
  int jm = -1;
  for (int j = 0; j < NOBJ; ++j) {
    if (A2[j * 8 + 5] == pid) { jm = j; break; }
  }
  bool has = (jm >= 0);
  const float* t1 = A2 + (has ? jm : 0) * 8;
  float cx2 = t1[0] * (float)OUT_W, cy2 = t1[1] * (float)OUT_H;
  float w2 = t1[2] * (float)OUT_W, h2 = t1[3] * (float)OUT_H;
  float x1t = cx2 - 0.5f * w2, y1t = cy2 - 0.5f * h2;
  float x2t = x1t + w2, y2t = y1t + h2;

  bool valid = has && (h > 0.f) && (w > 0.f) && (h2 > 0.f) && (w2 > 0.f);
  float vm = valid ? 1.f : 0.f;
  P.vm = vm;
  P.v = a1[6] * vm;
  P.wh[0] = (P.cxf - x1) * vm;  P.wh[1] = (x2 - P.cxf) * vm;
  P.wh[2] = (P.cyf - y1) * vm;  P.wh[3] = (y2 - P.cyf) * vm;
  P.wh[4] = (P.cxf - x1t) * vm; P.wh[5] = (x2t - P.cxf) * vm;
  P.wh[6] = (P.cyf - y1t) * vm; P.wh[7] = (y2t - P.cyf) * vm;
  P.ind = valid ? (cty * OUT_W + ctx) : 0;
  P.id = valid ? (int)pid : 0;
  return P;
}

__global__ void __launch_bounds__(256)
main_kernel(const float* __restrict__ cls,
            const float* __restrict__ identis,
            const float* __restrict__ W_id,
            const float* __restrict__ b_id,
            const float* __restrict__ ann1,
            const float* __restrict__ ann2,
            float* __restrict__ F) {
  if (blockIdx.x < NFOCAL) {
    /* ---------- focal branch ---------- */
    int blk = blockIdx.x;
    int b = blk / NFBLK;
    int bx = blk - b * NFBLK;
    int p = bx * 256 + threadIdx.x;

    __shared__ float s_ctx[64], s_cty[64], s_rad[64], s_inv[64];
    if (threadIdx.x < 64) {
      PrepOut P = prep_obj(ann1, ann2, b, threadIdx.x);
      s_ctx[threadIdx.x] = P.cxf;
      s_cty[threadIdx.x] = P.cyf;
      s_rad[threadIdx.x] = P.radius;
      s_inv[threadIdx.x] = P.inv2s2;
    }
    __syncthreads();

    float pos_l = 0.f, neg_l = 0.f, npos = 0.f;
    if (p < HW) {
      float xf = (float)(p % OUT_W);
      float yf = (float)(p / OUT_W);
      float gt = 0.f;
      #pragma unroll 8
      for (int o = 0; o < 64; ++o) {
        float dy = yf - s_cty[o];
        float dx = xf - s_ctx[o];
        float r = s_rad[o];
        if (fabsf(dy) <= r && fabsf(dx) <= r) {
          gt = fmaxf(gt, expf(-(dy * dy + dx * dx) * s_inv[o]));
        }
      }
      float x = cls[b * HW + p];
      float pr = 1.f / (1.f + expf(-x));
      pr = fminf(fmaxf(pr, 1e-4f), 0.9999f);
      if (gt == 1.f) {
        float om = 1.f - pr;
        pos_l = logf(pr) * om * om;
        npos = 1.f;
      } else {
        float omg = 1.f - gt;
        float w4 = omg * omg;
        w4 *= w4;
        neg_l = logf(1.f - pr) * pr * pr * w4;
      }
    }

    __shared__ float red[3][4];
    int wid = threadIdx.x >> 6, lane = threadIdx.x & 63;
    float a = waveRedSum(pos_l);
    float c = waveRedSum(neg_l);
    float n = waveRedSum(npos);
    if (lane == 0) { red[0][wid] = a; red[1][wid] = c; red[2][wid] = n; }
    __syncthreads();
    if (threadIdx.x == 0) {
      float pa = 0.f, pc = 0.f, pn = 0.f;
      for (int k = 0; k < 4; ++k) { pa += red[0][k]; pc += red[1][k]; pn += red[2][k]; }
      F[OF_FP + blk * 3 + 0] = pa;
      F[OF_FP + blk * 3 + 1] = pc;
      F[OF_FP + blk * 3 + 2] = pn;
    }
  } else {
    /* ---------- id-loss branch: one block per object ---------- */
    int o = blockIdx.x - NFOCAL;
    int b = o >> 6, i = o & 63;
    PrepOut P = prep_obj(ann1, ann2, b, i);
    if (P.vm == 0.f) {                 /* uniform across block */
      if (threadIdx.x == 0) F[OF_IDNLL + o] = 0.f;
      return;
    }
    int t = threadIdx.x;
    __shared__ float shf[EMB];
    __shared__ float slog[544];
    __shared__ float red4[4];
    int wid = t >> 6, lane = t & 63;

    float f = identis[(size_t)b * EMB * HW + (size_t)t * HW + P.ind];
    float n2 = waveRedSum(f * f);
    if (lane == 0) red4[wid] = n2;
    __syncthreads();
    float norm2 = red4[0] + red4[1] + red4[2] + red4[3];
    const float EMB_SCALE = 1.41421356237309515f * logf(536.0f);
    float scale = EMB_SCALE / fmaxf(sqrtf(norm2), 1e-12f);
    shf[t] = f * scale;
    __syncthreads();

    for (int c = t; c < NID; c += 256) {
      float acc = b_id[c];
      const float* wr = W_id + (size_t)c * EMB;
      #pragma unroll 4
      for (int k = 0; k < EMB; k += 4) {
        acc += shf[k] * wr[k] + shf[k + 1] * wr[k + 1] +
               shf[k + 2] * wr[k + 2] + shf[k + 3] * wr[k + 3];
      }
      slog[c] = acc;
    }
    __syncthreads();

    float mx = -1e30f;
    for (int c = t; c < NID; c += 256) mx = fmaxf(mx, slog[c]);
    mx = waveRedMax(mx);
    __syncthreads();
    if (lane == 0) red4[wid] = mx;
    __syncthreads();
    mx = fmaxf(fmaxf(red4[0], red4[1]), fmaxf(red4[2], red4[3]));

    float se = 0.f;
    for (int c = t; c < NID; c += 256) se += expf(slog[c] - mx);
    se = waveRedSum(se);
    __syncthreads();
    if (lane == 0) red4[wid] = se;
    __syncthreads();

    if (t == 0) {
      float sesum = red4[0] + red4[1] + red4[2] + red4[3];
      float lse = mx + logf(sesum);
      F[OF_IDNLL + o] = -P.v * (slog[P.id] - lse);
    }
  }
}

__global__ void __launch_bounds__(512)
final_kernel(const float* __restrict__ reg,
             const float* __restrict__ viss,
             const float* __restrict__ ann1,
             const float* __restrict__ ann2,
             const float* __restrict__ F,
             const float* __restrict__ s_det,
             const float* __restrict__ s_id,
             float* __restrict__ out) {
  int t = threadIdx.x;
  int b = t >> 6;           /* wave index = batch */
  int lane = t & 63;

  PrepOut P = prep_obj(ann1, ann2, b, lane);
  float msum = waveRedSum(P.vm);

  float rsum = 0.f, vsum = 0.f;
  if (P.vm > 0.f) {
    for (int c = 0; c < 8; ++c) {
      float pred = reg[(b * 8 + c) * HW + P.ind];
      float d = fabsf(pred - P.wh[c]);
      rsum += (d < 1.f) ? 0.5f * d * d : d - 0.5f;
    }
    float s = 1.f / (1.f + expf(-viss[b * HW + P.ind]));
    s = fminf(fmaxf(s, 1e-4f), 0.9999f);
    float d = fabsf(s - P.v);
    vsum += (d < 1.f) ? 0.5f * d * d : d - 0.5f;
  }
  rsum = waveRedSum(rsum);
  vsum = waveRedSum(vsum);

  /* focal partial reduce: 162 blocks per batch, strided by lane */
  float pa = 0.f, pc = 0.f, pn = 0.f;
  for (int e = lane; e < NFBLK; e += 64) {
    const float* fp = F + OF_FP + (b * NFBLK + e) * 3;
    pa += fp[0]; pc += fp[1]; pn += fp[2];
  }
  pa = waveRedSum(pa);
  pc = waveRedSum(pc);
  pn = waveRedSum(pn);

  /* id NLL reduce: 64 objects per batch, one per lane */
  float idv = waveRedSum(F[OF_IDNLL + b * 64 + lane]);

  __shared__ float L[8][4];
  if (lane == 0) {
    L[b][0] = (pn > 0.f) ? (-(pa + pc) / fmaxf(pn, 1.f)) : (-pc);
    L[b][1] = rsum / (msum + 0.0001f);
    L[b][2] = vsum / (msum + 0.0001f);
    L[b][3] = idv / fmaxf(msum, 1.f);
  }
  __syncthreads();
  if (t == 0) {
    float cl = 0.f, rl = 0.f, vl = 0.f, il = 0.f;
    for (int k = 0; k < 8; ++k) {
      cl += L[k][0]; rl += L[k][1]; vl += L[k][2]; il += L[k][3];
    }
    out[0] = cl / 8.f;
    out[1] = rl / 8.f;
    out[2] = vl / 8.f;
    out[3] = il / 8.f;
    out[4] = s_det[0];
    out[5] = s_id[0];
  }
}

extern "C" void kernel_launch(void* const* d_in, const int* in_sizes, int n_in,
                              void* d_out, int out_size, void* d_ws, size_t ws_size,
                              hipStream_t stream) {
  const float* cls     = (const float*)d_in[0];
  const float* reg     = (const float*)d_in[1];
  const float* viss    = (const float*)d_in[2];
  const float* identis = (const float*)d_in[3];
  const float* ann1    = (const float*)d_in[4];
  const float* ann2    = (const float*)d_in[5];
  const float* W_id    = (const float*)d_in[6];
  const float* b_id    = (const float*)d_in[7];
  const float* s_det   = (const float*)d_in[8];
  const float* s_id    = (const float*)d_in[9];
  float* F = (float*)d_ws;

  main_kernel<<<NFOCAL + NIDBLK, 256, 0, stream>>>(cls, identis, W_id, b_id,
                                                   ann1, ann2, F);
  final_kernel<<<1, 512, 0, stream>>>(reg, viss, ann1, ann2, F,
                                      s_det, s_id, (float*)d_out);
}